// Round 9
// baseline (140.455 us; speedup 1.0000x reference)
//
#include <hip/hip_runtime.h>

#define NSTATE 128
#define NM1    127
#define UDIM   4
#define NCOEF  35
#define CSTR   37

typedef float v2f __attribute__((ext_vector_type(2)));

// R9: three-pass algebraic restructure.
//  k_coeff: per-state moments of P_j = exp(logP0[s][j]) against w_j (w_self=0):
//           c0=SUM P, m=SUM P w, D=(mult/2) SUM P w w, E=(mult/6) SUM P w w w.
//  k_lse:   lse[t] = log(c0 + u.m + u^T D u + E(u,u,u))  -- 3rd-order Taylor of
//           log SUM_j P_j exp(u.w_j); |u.w| <= ~0.3 => truncation <= ~5e-4,
//           far under threshold. Thread-per-row, coeffs in LDS, NO shuffles.
//  k_out:   pure stream, thread-per-element: out[t][j] = logP0[s][j] + u.w_j - lse[t].
//           fillBuffer-shaped stores (256B/wave, 4KB/block contiguous).
// Coeff table (19KB) lives in the TAIL OF d_out: written by k_coeff, read by
// k_lse, then overwritten by k_out (stream-ordered, deterministic).

__device__ __forceinline__ float dot4(const float4 a, const float4 b) {
    return fmaf(a.x, b.x, fmaf(a.y, b.y, fmaf(a.z, b.z, a.w * b.w)));
}

// ---------------- k_coeff: per-state Taylor moments ----------------
__global__ __launch_bounds__(NSTATE) void k_coeff(
    const float* __restrict__ logP0, const float* __restrict__ W,
    float* __restrict__ coeff)
{
    __shared__ float red[NCOEF][NSTATE + 1];
    const int s = blockIdx.x, j = threadIdx.x;

    float wa[4] = {0.0f, 0.0f, 0.0f, 0.0f};
    if (j != s) {
        const int k = j - (j > s);
        const float4 w = *reinterpret_cast<const float4*>(W + ((size_t)s * NM1 + k) * UDIM);
        wa[0] = w.x; wa[1] = w.y; wa[2] = w.z; wa[3] = w.w;
    }
    const float P = __expf(logP0[s * NSTATE + j]);

    red[0][j] = P;
    #pragma unroll
    for (int a = 0; a < 4; ++a) red[1 + a][j] = P * wa[a];

    constexpr int PA_[10] = {0,0,0,0,1,1,1,2,2,3};
    constexpr int PB_[10] = {0,1,2,3,1,2,3,2,3,3};
    #pragma unroll
    for (int p = 0; p < 10; ++p) {
        const float mlt = (PA_[p] == PB_[p]) ? 0.5f : 1.0f;
        red[5 + p][j] = P * wa[PA_[p]] * wa[PB_[p]] * mlt;
    }
    constexpr int TA_[20] = {0,0,0,0,0,0,0,0,0,0,1,1,1,1,1,1,2,2,2,3};
    constexpr int TB_[20] = {0,0,0,0,1,1,1,2,2,3,1,1,1,2,2,3,2,2,3,3};
    constexpr int TC_[20] = {0,1,2,3,1,2,3,2,3,3,1,2,3,2,3,3,2,3,3,3};
    #pragma unroll
    for (int q = 0; q < 20; ++q) {
        const int a = TA_[q], b = TB_[q], c = TC_[q];
        const float mlt = (a == b && b == c) ? (1.0f / 6.0f)
                        : ((a == b || b == c) ? 0.5f : 1.0f);
        red[15 + q][j] = P * wa[a] * wa[b] * wa[c] * mlt;
    }
    __syncthreads();

    if (j < NCOEF) {
        float acc = 0.0f;
        #pragma unroll 4
        for (int i = 0; i < NSTATE; ++i) acc += red[j][i];
        coeff[s * CSTR + j] = acc;
    }
}

// ---------------- k_lse: thread-per-row polynomial lse ----------------
__global__ __launch_bounds__(256) void k_lse(
    const int* __restrict__ x, const float* __restrict__ u,
    const float* __restrict__ coeff, float* __restrict__ lse, int T)
{
    __shared__ float C[NSTATE * CSTR];
    for (int i = threadIdx.x; i < NSTATE * CSTR; i += blockDim.x) C[i] = coeff[i];
    __syncthreads();

    const int stride = gridDim.x * blockDim.x;
    for (int t = blockIdx.x * blockDim.x + threadIdx.x; t < T; t += stride) {
        const int s = x[t];
        const float4 uv = *reinterpret_cast<const float4*>(u + (size_t)t * UDIM);
        const float ua[4] = {uv.x, uv.y, uv.z, uv.w};
        const float* Cb = &C[s * CSTR];

        float z = Cb[0];
        #pragma unroll
        for (int a = 0; a < 4; ++a) z = fmaf(ua[a], Cb[1 + a], z);

        constexpr int PA_[10] = {0,0,0,0,1,1,1,2,2,3};
        constexpr int PB_[10] = {0,1,2,3,1,2,3,2,3,3};
        float uu[10];
        #pragma unroll
        for (int p = 0; p < 10; ++p) uu[p] = ua[PA_[p]] * ua[PB_[p]];
        #pragma unroll
        for (int p = 0; p < 10; ++p) z = fmaf(uu[p], Cb[5 + p], z);

        constexpr int TQ_[20] = {0,1,2,3,4,5,6,7,8,9,4,5,6,7,8,9,7,8,9,9};
        constexpr int TC_[20] = {0,1,2,3,1,2,3,2,3,3,1,2,3,2,3,3,2,3,3,3};
        #pragma unroll
        for (int q = 0; q < 20; ++q)
            z = fmaf(uu[TQ_[q]] * ua[TC_[q]], Cb[15 + q], z);

        lse[t] = __logf(z);
    }
}

// ---------------- k_out: pure-stream element pass ----------------
__global__ __launch_bounds__(256) void k_out(
    const int* __restrict__ x, const float* __restrict__ u,
    const float* __restrict__ logP0, const float* __restrict__ W,
    const float* __restrict__ lse, float* __restrict__ out, size_t total)
{
    const size_t stride = (size_t)gridDim.x * blockDim.x;
    size_t e = (size_t)blockIdx.x * blockDim.x + threadIdx.x;
    #pragma unroll 2
    for (; e < total; e += stride) {
        const int t  = (int)(e >> 7);
        const int j  = (int)(e & (NSTATE - 1));
        const int tu = __builtin_amdgcn_readfirstlane(t);   // wave-uniform row
        const int s  = x[tu];
        const float4 uv = *reinterpret_cast<const float4*>(u + (size_t)tu * UDIM);
        const float  L  = lse[tu];
        float st = 0.0f;
        if (j != s) {
            const int k = j - (j > s);
            const float4 w = *reinterpret_cast<const float4*>(W + ((size_t)s * NM1 + k) * UDIM);
            st = dot4(uv, w);
        }
        out[e] = logP0[s * NSTATE + j] + st - L;
    }
}

// ---------------- fallback (ws too small): R8-style direct kernel ----------------
__global__ __launch_bounds__(256) void k_fallback(
    const int* __restrict__ x_curr, const float* __restrict__ u_curr,
    const float* __restrict__ logP0, const float* __restrict__ W,
    float* __restrict__ out, int T)
{
    const int lane    = threadIdx.x & 63;
    const int wave_id = (blockIdx.x * blockDim.x + threadIdx.x) >> 6;
    const int nwaves  = (gridDim.x * blockDim.x) >> 6;
    const int j0 = 2 * lane, j1 = j0 + 1;
    for (int t = wave_id; t < T; t += nwaves) {
        int s = x_curr[t];
        s = __builtin_amdgcn_readfirstlane(s);
        const float4 uv = *reinterpret_cast<const float4*>(u_curr + (size_t)t * UDIM);
        float st0 = 0.0f, st1 = 0.0f;
        if (j0 != s) {
            const int k = j0 - (j0 > s);
            const float4 w = *reinterpret_cast<const float4*>(W + ((size_t)s * NM1 + k) * UDIM);
            st0 = dot4(uv, w);
        }
        if (j1 != s) {
            const int k = j1 - (j1 > s);
            const float4 w = *reinterpret_cast<const float4*>(W + ((size_t)s * NM1 + k) * UDIM);
            st1 = dot4(uv, w);
        }
        const float2 lp = *reinterpret_cast<const float2*>(logP0 + (size_t)s * NSTATE + j0);
        const float v0 = lp.x + st0, v1 = lp.y + st1;
        float ex = __expf(v0) + __expf(v1);
        #pragma unroll
        for (int off = 32; off >= 1; off >>= 1)
            ex += __shfl_xor(ex, off, 64);
        const float l = __logf(ex);
        v2f o; o[0] = v0 - l; o[1] = v1 - l;
        *reinterpret_cast<v2f*>(out + (size_t)t * NSTATE + j0) = o;
    }
}

extern "C" void kernel_launch(void* const* d_in, const int* in_sizes, int n_in,
                              void* d_out, int out_size, void* d_ws, size_t ws_size,
                              hipStream_t stream) {
    const int*   x_curr = (const int*)  d_in[0];
    const float* u_curr = (const float*)d_in[1];
    const float* logP0  = (const float*)d_in[2];
    const float* W      = (const float*)d_in[3];
    float*       out    = (float*)d_out;

    const int    T     = in_sizes[0];
    const size_t total = (size_t)T * NSTATE;
    const size_t lse_need = (size_t)T * sizeof(float);

    if (ws_size < lse_need || (size_t)out_size < (size_t)(NSTATE * CSTR + 64)) {
        hipLaunchKernelGGL(k_fallback, dim3(2048), dim3(256), 0, stream,
                           x_curr, u_curr, logP0, W, out, T);
        return;
    }

    float* lse = (float*)d_ws;
    // coeff table in the tail of d_out (16B-aligned element offset); read by
    // k_lse before k_out overwrites that region (same-stream ordering).
    float* coeff = out + (((size_t)out_size - (size_t)(NSTATE * CSTR)) & ~(size_t)3);

    int nblk_lse = (T + 255) / 256;
    if (nblk_lse > 2048) nblk_lse = 2048;

    hipLaunchKernelGGL(k_coeff, dim3(NSTATE), dim3(NSTATE), 0, stream, logP0, W, coeff);
    hipLaunchKernelGGL(k_lse, dim3(nblk_lse), dim3(256), 0, stream,
                       x_curr, u_curr, coeff, lse, T);
    hipLaunchKernelGGL(k_out, dim3(2048), dim3(256), 0, stream,
                       x_curr, u_curr, logP0, W, lse, out, total);
}

// Round 10
// 96.877 us; speedup vs baseline: 1.4498x; 1.4498x over previous
//
#include <hip/hip_runtime.h>

#define NSTATE 128
#define NM1    127
#define UDIM   4

typedef float v2f __attribute__((ext_vector_type(2)));

// R10: blocked-span write streams.
// Each wave owns a CONTIGUOUS span of R rows (R ~ 248, multiple of 4); 2048
// waves total (8/CU, fillBuffer's regime) instead of 8192 strided streams.
// Per pipeline group: 4 consecutive rows -> x loaded as ONE int4, 4 uniform
// u loads, 8 Wt loads (R8 de-interleaved table), 4 lp loads, then 4
// consecutive 512B nt-stores = 2KB sequential per iteration per wave.
// DRAM page locality: each wave's store stream is purely sequential.
// No-max softmax validated R2-R9 (absmax 0.0625 vs thr 0.186).

__device__ __forceinline__ float dot4(const float4 a, const float4 b) {
    return fmaf(a.x, b.x, fmaf(a.y, b.y, fmaf(a.z, b.z, a.w * b.w)));
}

// ---------------- pre-pass: build de-interleaved padded weight table ----------------
__global__ __launch_bounds__(128) void k_build_wt(
    const float* __restrict__ W, float4* __restrict__ Wt)
{
    const int s = blockIdx.x;      // 0..127
    const int j = threadIdx.x;     // 0..127
    float4 v = make_float4(0.0f, 0.0f, 0.0f, 0.0f);
    if (j != s) {
        const int k = j - (j > s);
        v = *reinterpret_cast<const float4*>(W + ((size_t)s * NM1 + k) * UDIM);
    }
    Wt[(((j & 1) * NSTATE + s) << 6) + (j >> 1)] = v;
}

// ---------------- hot kernel ----------------
__global__ __launch_bounds__(256, 2) void llm_blocked(
    const int*    __restrict__ x_curr,
    const float*  __restrict__ u_curr,
    const float*  __restrict__ logP0,
    const float4* __restrict__ Wt,
    float*        __restrict__ out,
    int T, int R)
{
    const int lane = threadIdx.x & 63;
    const int wave = (blockIdx.x * blockDim.x + threadIdx.x) >> 6;
    const int t0   = wave * R;
    if (t0 >= T) return;
    const int tend = (t0 + R < T) ? (t0 + R) : T;
    const int j0   = 2 * lane;

    auto xb = [&](int t) { return (t < T - 4) ? t : (T - 4); };  // int4-safe base

    // ---------------- prologue: group A (tA) + group B (tA+4) x/u ----------------
    int tA = t0;
    int4 xA = *reinterpret_cast<const int4*>(x_curr + tA);
    int4 xB = *reinterpret_cast<const int4*>(x_curr + xb(tA + 4));
    const int tBb = xb(tA + 4);
    float4 uA0 = *reinterpret_cast<const float4*>(u_curr + (size_t)(tA + 0) * UDIM);
    float4 uA1 = *reinterpret_cast<const float4*>(u_curr + (size_t)(tA + 1) * UDIM);
    float4 uA2 = *reinterpret_cast<const float4*>(u_curr + (size_t)(tA + 2) * UDIM);
    float4 uA3 = *reinterpret_cast<const float4*>(u_curr + (size_t)(tA + 3) * UDIM);
    float4 uB0 = *reinterpret_cast<const float4*>(u_curr + (size_t)(tBb + 0) * UDIM);
    float4 uB1 = *reinterpret_cast<const float4*>(u_curr + (size_t)(tBb + 1) * UDIM);
    float4 uB2 = *reinterpret_cast<const float4*>(u_curr + (size_t)(tBb + 2) * UDIM);
    float4 uB3 = *reinterpret_cast<const float4*>(u_curr + (size_t)(tBb + 3) * UDIM);

    int sA0 = __builtin_amdgcn_readfirstlane(xA.x);
    int sA1 = __builtin_amdgcn_readfirstlane(xA.y);
    int sA2 = __builtin_amdgcn_readfirstlane(xA.z);
    int sA3 = __builtin_amdgcn_readfirstlane(xA.w);

    float4 pA0 = Wt[(sA0 << 6) + lane], qA0 = Wt[((NSTATE + sA0) << 6) + lane];
    float4 pA1 = Wt[(sA1 << 6) + lane], qA1 = Wt[((NSTATE + sA1) << 6) + lane];
    float4 pA2 = Wt[(sA2 << 6) + lane], qA2 = Wt[((NSTATE + sA2) << 6) + lane];
    float4 pA3 = Wt[(sA3 << 6) + lane], qA3 = Wt[((NSTATE + sA3) << 6) + lane];
    float2 lpA0 = *reinterpret_cast<const float2*>(logP0 + (size_t)sA0 * NSTATE + j0);
    float2 lpA1 = *reinterpret_cast<const float2*>(logP0 + (size_t)sA1 * NSTATE + j0);
    float2 lpA2 = *reinterpret_cast<const float2*>(logP0 + (size_t)sA2 * NSTATE + j0);
    float2 lpA3 = *reinterpret_cast<const float2*>(logP0 + (size_t)sA3 * NSTATE + j0);

    // ---------------- main pipelined loop (full groups only) ----------------
    while (tA + 4 < tend) {
        // phase 1: prefetch x/u for group C = tA+8
        const int tCb = xb(tA + 8);
        int4 xC = *reinterpret_cast<const int4*>(x_curr + tCb);
        float4 uC0 = *reinterpret_cast<const float4*>(u_curr + (size_t)(tCb + 0) * UDIM);
        float4 uC1 = *reinterpret_cast<const float4*>(u_curr + (size_t)(tCb + 1) * UDIM);
        float4 uC2 = *reinterpret_cast<const float4*>(u_curr + (size_t)(tCb + 2) * UDIM);
        float4 uC3 = *reinterpret_cast<const float4*>(u_curr + (size_t)(tCb + 3) * UDIM);
        __builtin_amdgcn_sched_barrier(0);

        // phase 2: resolve group B states + issue Wt/lp loads for B
        const int sB0 = __builtin_amdgcn_readfirstlane(xB.x);
        const int sB1 = __builtin_amdgcn_readfirstlane(xB.y);
        const int sB2 = __builtin_amdgcn_readfirstlane(xB.z);
        const int sB3 = __builtin_amdgcn_readfirstlane(xB.w);
        float4 pB0 = Wt[(sB0 << 6) + lane], qB0 = Wt[((NSTATE + sB0) << 6) + lane];
        float4 pB1 = Wt[(sB1 << 6) + lane], qB1 = Wt[((NSTATE + sB1) << 6) + lane];
        float4 pB2 = Wt[(sB2 << 6) + lane], qB2 = Wt[((NSTATE + sB2) << 6) + lane];
        float4 pB3 = Wt[(sB3 << 6) + lane], qB3 = Wt[((NSTATE + sB3) << 6) + lane];
        float2 lpB0 = *reinterpret_cast<const float2*>(logP0 + (size_t)sB0 * NSTATE + j0);
        float2 lpB1 = *reinterpret_cast<const float2*>(logP0 + (size_t)sB1 * NSTATE + j0);
        float2 lpB2 = *reinterpret_cast<const float2*>(logP0 + (size_t)sB2 * NSTATE + j0);
        float2 lpB3 = *reinterpret_cast<const float2*>(logP0 + (size_t)sB3 * NSTATE + j0);
        __builtin_amdgcn_sched_barrier(0);

        // phase 3: compute group A (4 rows, butterflies interleaved)
        const float v00 = lpA0.x + dot4(uA0, pA0), v01 = lpA0.y + dot4(uA0, qA0);
        const float v10 = lpA1.x + dot4(uA1, pA1), v11 = lpA1.y + dot4(uA1, qA1);
        const float v20 = lpA2.x + dot4(uA2, pA2), v21 = lpA2.y + dot4(uA2, qA2);
        const float v30 = lpA3.x + dot4(uA3, pA3), v31 = lpA3.y + dot4(uA3, qA3);

        float e0 = __expf(v00) + __expf(v01);
        float e1 = __expf(v10) + __expf(v11);
        float e2 = __expf(v20) + __expf(v21);
        float e3 = __expf(v30) + __expf(v31);
        #pragma unroll
        for (int off = 32; off >= 1; off >>= 1) {
            e0 += __shfl_xor(e0, off, 64);
            e1 += __shfl_xor(e1, off, 64);
            e2 += __shfl_xor(e2, off, 64);
            e3 += __shfl_xor(e3, off, 64);
        }
        const float l0 = __logf(e0), l1 = __logf(e1);
        const float l2 = __logf(e2), l3 = __logf(e3);
        __builtin_amdgcn_sched_barrier(0);

        // phase 4: 4 consecutive-row stores = 2KB sequential
        v2f o0, o1, o2, o3;
        o0[0] = v00 - l0; o0[1] = v01 - l0;
        o1[0] = v10 - l1; o1[1] = v11 - l1;
        o2[0] = v20 - l2; o2[1] = v21 - l2;
        o3[0] = v30 - l3; o3[1] = v31 - l3;
        float* ob = out + (size_t)tA * NSTATE + j0;
        __builtin_nontemporal_store(o0, reinterpret_cast<v2f*>(ob));
        __builtin_nontemporal_store(o1, reinterpret_cast<v2f*>(ob + NSTATE));
        __builtin_nontemporal_store(o2, reinterpret_cast<v2f*>(ob + 2 * NSTATE));
        __builtin_nontemporal_store(o3, reinterpret_cast<v2f*>(ob + 3 * NSTATE));
        __builtin_amdgcn_sched_barrier(0);

        // rotate
        tA += 4;
        sA0 = sB0; sA1 = sB1; sA2 = sB2; sA3 = sB3;
        uA0 = uB0; uA1 = uB1; uA2 = uB2; uA3 = uB3;
        pA0 = pB0; pA1 = pB1; pA2 = pB2; pA3 = pB3;
        qA0 = qB0; qA1 = qB1; qA2 = qB2; qA3 = qB3;
        lpA0 = lpB0; lpA1 = lpB1; lpA2 = lpB2; lpA3 = lpB3;
        xB = xC;
        uB0 = uC0; uB1 = uC1; uB2 = uC2; uB3 = uC3;
    }

    // ---------------- drain group A: rows tA .. tend-1 (guarded) ----------------
    {
        const float v00 = lpA0.x + dot4(uA0, pA0), v01 = lpA0.y + dot4(uA0, qA0);
        const float v10 = lpA1.x + dot4(uA1, pA1), v11 = lpA1.y + dot4(uA1, qA1);
        const float v20 = lpA2.x + dot4(uA2, pA2), v21 = lpA2.y + dot4(uA2, qA2);
        const float v30 = lpA3.x + dot4(uA3, pA3), v31 = lpA3.y + dot4(uA3, qA3);
        float e0 = __expf(v00) + __expf(v01);
        float e1 = __expf(v10) + __expf(v11);
        float e2 = __expf(v20) + __expf(v21);
        float e3 = __expf(v30) + __expf(v31);
        #pragma unroll
        for (int off = 32; off >= 1; off >>= 1) {
            e0 += __shfl_xor(e0, off, 64);
            e1 += __shfl_xor(e1, off, 64);
            e2 += __shfl_xor(e2, off, 64);
            e3 += __shfl_xor(e3, off, 64);
        }
        const float l0 = __logf(e0), l1 = __logf(e1);
        const float l2 = __logf(e2), l3 = __logf(e3);
        v2f o0, o1, o2, o3;
        o0[0] = v00 - l0; o0[1] = v01 - l0;
        o1[0] = v10 - l1; o1[1] = v11 - l1;
        o2[0] = v20 - l2; o2[1] = v21 - l2;
        o3[0] = v30 - l3; o3[1] = v31 - l3;
        float* ob = out + (size_t)tA * NSTATE + j0;
        if (tA + 0 < tend) __builtin_nontemporal_store(o0, reinterpret_cast<v2f*>(ob));
        if (tA + 1 < tend) __builtin_nontemporal_store(o1, reinterpret_cast<v2f*>(ob + NSTATE));
        if (tA + 2 < tend) __builtin_nontemporal_store(o2, reinterpret_cast<v2f*>(ob + 2 * NSTATE));
        if (tA + 3 < tend) __builtin_nontemporal_store(o3, reinterpret_cast<v2f*>(ob + 3 * NSTATE));
    }
}

// ---------------- fallback (ws too small or tiny T) ----------------
__global__ __launch_bounds__(256) void k_fallback(
    const int* __restrict__ x_curr, const float* __restrict__ u_curr,
    const float* __restrict__ logP0, const float* __restrict__ W,
    float* __restrict__ out, int T)
{
    const int lane    = threadIdx.x & 63;
    const int wave_id = (blockIdx.x * blockDim.x + threadIdx.x) >> 6;
    const int nwaves  = (gridDim.x * blockDim.x) >> 6;
    const int j0 = 2 * lane, j1 = j0 + 1;
    for (int t = wave_id; t < T; t += nwaves) {
        int s = x_curr[t];
        s = __builtin_amdgcn_readfirstlane(s);
        const float4 uv = *reinterpret_cast<const float4*>(u_curr + (size_t)t * UDIM);
        float st0 = 0.0f, st1 = 0.0f;
        if (j0 != s) {
            const int k = j0 - (j0 > s);
            const float4 w = *reinterpret_cast<const float4*>(W + ((size_t)s * NM1 + k) * UDIM);
            st0 = dot4(uv, w);
        }
        if (j1 != s) {
            const int k = j1 - (j1 > s);
            const float4 w = *reinterpret_cast<const float4*>(W + ((size_t)s * NM1 + k) * UDIM);
            st1 = dot4(uv, w);
        }
        const float2 lp = *reinterpret_cast<const float2*>(logP0 + (size_t)s * NSTATE + j0);
        const float v0 = lp.x + st0, v1 = lp.y + st1;
        float e = __expf(v0) + __expf(v1);
        #pragma unroll
        for (int off = 32; off >= 1; off >>= 1)
            e += __shfl_xor(e, off, 64);
        const float l = __logf(e);
        v2f o; o[0] = v0 - l; o[1] = v1 - l;
        *reinterpret_cast<v2f*>(out + (size_t)t * NSTATE + j0) = o;
    }
}

extern "C" void kernel_launch(void* const* d_in, const int* in_sizes, int n_in,
                              void* d_out, int out_size, void* d_ws, size_t ws_size,
                              hipStream_t stream) {
    const int*   x_curr = (const int*)  d_in[0];
    const float* u_curr = (const float*)d_in[1];
    const float* logP0  = (const float*)d_in[2];
    const float* W      = (const float*)d_in[3];
    float*       out    = (float*)d_out;

    const int T = in_sizes[0];
    const size_t need = (size_t)2 * NSTATE * 64 * sizeof(float4);  // 256 KB

    if (ws_size < need || T < 16 || (T & 3)) {
        hipLaunchKernelGGL(k_fallback, dim3(2048), dim3(256), 0, stream,
                           x_curr, u_curr, logP0, W, out, T);
        return;
    }

    float4* Wt = (float4*)d_ws;
    hipLaunchKernelGGL(k_build_wt, dim3(NSTATE), dim3(NSTATE), 0, stream, W, Wt);

    // 512 blocks x 256 threads = 2048 waves, each owning a contiguous span of
    // R rows (R multiple of 4): 8 waves/CU, one sequential write stream each.
    const int nwaves = 2048;
    const int R = (((T + nwaves - 1) / nwaves) + 3) & ~3;
    hipLaunchKernelGGL(llm_blocked, dim3(512), dim3(256), 0, stream,
                       x_curr, u_curr, logP0, Wt, out, T, R);
}

// Round 11
// 70.678 us; speedup vs baseline: 1.9872x; 1.3707x over previous
//
#include <hip/hip_runtime.h>

#define NSTATE 128
#define NM1    127
#define UDIM   4
#define CHUNK  512
#define BLOCKT 256

typedef float v4f __attribute__((ext_vector_type(4)));

// R11: chunk-local bucket-by-state.
// Block owns 512 contiguous rows. Phase 1: LDS histogram -> scan -> bucket
// lists. Phase 2: wave handles states s = wv, wv+4, ...; per bucket loads
// W-fragments + logP0 ONCE (2.5KB amortized over ~4 rows: 4x read cut vs
// per-row re-gather), then processes rows TWO per wave: lanes 0-31 = row A,
// lanes 32-63 = row B, each lane 4 cols -> one nt wave-store covers 2 full
// rows (8 full 128B lines). Butterfly = 5 steps within 32-lane halves.
// Writes confined to the block's 256KB window (page locality); nt bypasses
// L2 so the hot Wt table stays resident.
// No-max softmax validated R2-R10 (absmax 0.0625 vs thr 0.186).

__device__ __forceinline__ float dot4(const float4 a, const float4 b) {
    return fmaf(a.x, b.x, fmaf(a.y, b.y, fmaf(a.z, b.z, a.w * b.w)));
}

// ---------------- pre-pass: de-interleaved padded weight table (R8) ----------------
__global__ __launch_bounds__(128) void k_build_wt(
    const float* __restrict__ W, float4* __restrict__ Wt)
{
    const int s = blockIdx.x;      // 0..127
    const int j = threadIdx.x;     // 0..127
    float4 v = make_float4(0.0f, 0.0f, 0.0f, 0.0f);
    if (j != s) {
        const int k = j - (j > s);
        v = *reinterpret_cast<const float4*>(W + ((size_t)s * NM1 + k) * UDIM);
    }
    Wt[(((j & 1) * NSTATE + s) << 6) + (j >> 1)] = v;
}

// ---------------- hot kernel ----------------
__global__ __launch_bounds__(256) void k_chunked(
    const int*    __restrict__ x_curr,
    const float*  __restrict__ u_curr,
    const float*  __restrict__ logP0,
    const float4* __restrict__ Wt,
    float*        __restrict__ out,
    int T)
{
    __shared__ int cnt[NSTATE], basep[NSTATE], off[NSTATE];
    __shared__ int sa[NSTATE], sb[NSTATE];
    __shared__ unsigned short list[CHUNK];

    const int tid    = threadIdx.x;
    const int chunk0 = blockIdx.x * CHUNK;
    const int cend   = (T - chunk0 < CHUNK) ? (T - chunk0) : CHUNK;

    if (tid < NSTATE) { cnt[tid] = 0; off[tid] = 0; }
    __syncthreads();

    // ---- phase 1a: count ----
    int xloc[CHUNK / BLOCKT];
    #pragma unroll
    for (int c = 0; c < CHUNK / BLOCKT; ++c) {
        const int i = tid + c * BLOCKT;
        xloc[c] = (i < cend) ? x_curr[chunk0 + i] : -1;
        if (xloc[c] >= 0) atomicAdd(&cnt[xloc[c]], 1);
    }
    __syncthreads();

    // ---- phase 1b: exclusive scan over 128 bins ----
    if (tid < NSTATE) sa[tid] = cnt[tid];
    __syncthreads();
    {
        int* src = sa; int* dst = sb;
        #pragma unroll
        for (int o = 1; o < NSTATE; o <<= 1) {
            if (tid < NSTATE) dst[tid] = (tid >= o) ? (src[tid] + src[tid - o]) : src[tid];
            __syncthreads();
            int* tmp = src; src = dst; dst = tmp;
        }
        if (tid < NSTATE) basep[tid] = src[tid] - cnt[tid];
    }
    __syncthreads();

    // ---- phase 1c: place ----
    #pragma unroll
    for (int c = 0; c < CHUNK / BLOCKT; ++c) {
        const int i = tid + c * BLOCKT;
        if (xloc[c] >= 0) {
            const int p = basep[xloc[c]] + atomicAdd(&off[xloc[c]], 1);
            list[p] = (unsigned short)i;
        }
    }
    __syncthreads();

    // ---- phase 2: per-bucket compute, 2 rows per wave ----
    const int lane = tid & 63;
    const int wv   = tid >> 6;      // 0..3
    const int h    = lane >> 5;     // half: 0 = row A, 1 = row B
    const int lh   = lane & 31;     // lane within half
    const int j0   = 4 * lh;        // this lane's 4 columns

    for (int s = wv; s < NSTATE; s += 4) {
        const int n = cnt[s];
        if (n == 0) continue;
        const int b = basep[s];

        // per-bucket operands (loaded once; halves broadcast-share lines)
        const float4 wA = Wt[(s << 6) + 2 * lh];                 // col 4lh
        const float4 wB = Wt[((NSTATE + s) << 6) + 2 * lh];      // col 4lh+1
        const float4 wC = Wt[(s << 6) + 2 * lh + 1];             // col 4lh+2
        const float4 wD = Wt[((NSTATE + s) << 6) + 2 * lh + 1];  // col 4lh+3
        const float4 lp = *reinterpret_cast<const float4*>(logP0 + s * NSTATE + j0);

        const int npair = (n + 1) >> 1;

        // first pair (odd n duplicates row A in half B: identical bytes stored twice)
        int rA0 = chunk0 + list[b];
        int rB0 = (n > 1) ? (chunk0 + list[b + 1]) : rA0;
        int r   = h ? rB0 : rA0;
        float4 uv = *reinterpret_cast<const float4*>(u_curr + (size_t)r * UDIM);

        for (int p = 0; p < npair; ++p) {
            // prefetch next pair's row id + u
            int rn = r; float4 un = uv;
            if (p + 1 < npair) {
                const int e0 = b + 2 * (p + 1);
                const int nA = chunk0 + list[e0];
                const int nB = (2 * (p + 1) + 1 < n) ? (chunk0 + list[e0 + 1]) : nA;
                rn = h ? nB : nA;
                un = *reinterpret_cast<const float4*>(u_curr + (size_t)rn * UDIM);
            }

            const float v0 = lp.x + dot4(uv, wA);
            const float v1 = lp.y + dot4(uv, wB);
            const float v2 = lp.z + dot4(uv, wC);
            const float v3 = lp.w + dot4(uv, wD);

            float e = (__expf(v0) + __expf(v1)) + (__expf(v2) + __expf(v3));
            #pragma unroll
            for (int o = 16; o >= 1; o >>= 1)
                e += __shfl_xor(e, o, 64);      // stays within 32-lane half
            const float l = __logf(e);

            v4f ov;
            ov[0] = v0 - l; ov[1] = v1 - l; ov[2] = v2 - l; ov[3] = v3 - l;
            __builtin_nontemporal_store(
                ov, reinterpret_cast<v4f*>(out + (size_t)r * NSTATE + j0));

            r = rn; uv = un;
        }
    }
}

// ---------------- fallback (ws too small): R8-style direct kernel ----------------
__global__ __launch_bounds__(256) void k_fallback(
    const int* __restrict__ x_curr, const float* __restrict__ u_curr,
    const float* __restrict__ logP0, const float* __restrict__ W,
    float* __restrict__ out, int T)
{
    const int lane    = threadIdx.x & 63;
    const int wave_id = (blockIdx.x * blockDim.x + threadIdx.x) >> 6;
    const int nwaves  = (gridDim.x * blockDim.x) >> 6;
    const int j0 = 2 * lane, j1 = j0 + 1;
    for (int t = wave_id; t < T; t += nwaves) {
        int s = x_curr[t];
        s = __builtin_amdgcn_readfirstlane(s);
        const float4 uv = *reinterpret_cast<const float4*>(u_curr + (size_t)t * UDIM);
        float st0 = 0.0f, st1 = 0.0f;
        if (j0 != s) {
            const int k = j0 - (j0 > s);
            const float4 w = *reinterpret_cast<const float4*>(W + ((size_t)s * NM1 + k) * UDIM);
            st0 = dot4(uv, w);
        }
        if (j1 != s) {
            const int k = j1 - (j1 > s);
            const float4 w = *reinterpret_cast<const float4*>(W + ((size_t)s * NM1 + k) * UDIM);
            st1 = dot4(uv, w);
        }
        const float2 lp = *reinterpret_cast<const float2*>(logP0 + (size_t)s * NSTATE + j0);
        const float v0 = lp.x + st0, v1 = lp.y + st1;
        float e = __expf(v0) + __expf(v1);
        #pragma unroll
        for (int o = 32; o >= 1; o >>= 1)
            e += __shfl_xor(e, o, 64);
        const float l = __logf(e);
        float2 o2; o2.x = v0 - l; o2.y = v1 - l;
        *reinterpret_cast<float2*>(out + (size_t)t * NSTATE + j0) = o2;
    }
}

extern "C" void kernel_launch(void* const* d_in, const int* in_sizes, int n_in,
                              void* d_out, int out_size, void* d_ws, size_t ws_size,
                              hipStream_t stream) {
    const int*   x_curr = (const int*)  d_in[0];
    const float* u_curr = (const float*)d_in[1];
    const float* logP0  = (const float*)d_in[2];
    const float* W      = (const float*)d_in[3];
    float*       out    = (float*)d_out;

    const int T = in_sizes[0];
    const size_t need = (size_t)2 * NSTATE * 64 * sizeof(float4);  // 256 KB

    if (ws_size < need) {
        hipLaunchKernelGGL(k_fallback, dim3(2048), dim3(256), 0, stream,
                           x_curr, u_curr, logP0, W, out, T);
        return;
    }

    float4* Wt = (float4*)d_ws;
    hipLaunchKernelGGL(k_build_wt, dim3(NSTATE), dim3(NSTATE), 0, stream, W, Wt);

    const int nblk = (T + CHUNK - 1) / CHUNK;   // 977 blocks at T=500K
    hipLaunchKernelGGL(k_chunked, dim3(nblk), dim3(BLOCKT), 0, stream,
                       x_curr, u_curr, logP0, Wt, out, T);
}